// Round 1
// 256.259 us; speedup vs baseline: 1.0311x; 1.0311x over previous
//
#include <hip/hip_runtime.h>
#include <hip/hip_bf16.h>

#define CIN 512
#define NPIX 4096
#define MIDC 64
#define BATCH 4

typedef __hip_bfloat16 bf16;
typedef __attribute__((ext_vector_type(8))) short short8;
typedef __attribute__((ext_vector_type(16))) float f32x16;
typedef __attribute__((ext_vector_type(4))) float f32x4;

#define MFMA16(a, b, c) __builtin_amdgcn_mfma_f32_16x16x32_bf16(a, b, c, 0, 0, 0)
#define MFMA32(a, b, c) __builtin_amdgcn_mfma_f32_32x32x16_bf16(a, b, c, 0, 0, 0)

// cheap fp32 -> bf16 (round-half-up; inputs finite, no NaN path needed)
__device__ __forceinline__ short f2bs(float f) {
    unsigned u = __float_as_uint(f);
    return (short)((u + 0x8000u) >> 16);
}
// pack two fp32 -> bf16x2 in one uint (lo = a, hi = b)
__device__ __forceinline__ unsigned pack2bf(float a, float b) {
    unsigned ua = __float_as_uint(a), ub = __float_as_uint(b);
    return ((ua + 0x8000u) >> 16) | ((ub + 0x8000u) & 0xFFFF0000u);
}

// load 8 consecutive fp32 elements, convert to bf16 shorts (packed)
__device__ __forceinline__ short8 load8f(const float* p, size_t idx) {
    const float* q = p + idx;
    float4 u = *(const float4*)q;
    float4 v = *(const float4*)(q + 4);
    union { unsigned w[4]; short8 s; } r;
    r.w[0] = pack2bf(u.x, u.y);
    r.w[1] = pack2bf(u.z, u.w);
    r.w[2] = pack2bf(v.x, v.y);
    r.w[3] = pack2bf(v.z, v.w);
    return r.s;
}

// kp-row permutation for ck staging: within each 16, swap quartets [4,8)<->[8,12).
__device__ __forceinline__ int sigma16(int p) {
    int g = (p >> 2) & 3;
    return (g == 1) ? p + 4 : (g == 2) ? p - 4 : p;
}

// ---------------------------------------------------------------------------
// Projection restructure (round 1): each block stages its 64n x-tile ONCE per
// c-quarter and loops ALL W row-blocks over it, acc held in registers for the
// full o-range. W tiles double-buffered: one barrier per step.
// LDS tile stride: 128 c + 8 pad shorts (same bank pattern class as old 72).
// ---------------------------------------------------------------------------
#define TS 136

// stage x[b][cq*128 .. +128][n0 .. n0+64] transposed into xT[64][TS]
__device__ __forceinline__ void stage_x(const float* __restrict__ x, int b, int n0,
                                        int cq, short* xT, int tid) {
    #pragma unroll
    for (int i = 0; i < 4; ++i) {
        int idx = tid + i * 256;
        int cc = idx >> 3, nn = (idx & 7) * 8;
        short8 v = load8f(x, (size_t)b * CIN * NPIX + (size_t)(cq * 128 + cc) * NPIX + n0 + nn);
        #pragma unroll
        for (int e = 0; e < 8; ++e) xT[(nn + e) * TS + cc] = v[e];
    }
}
// stage W rows [rowbase .. +64] x c [cq*128 .. +128] into Wt[64][TS] (row-major copy)
__device__ __forceinline__ void stage_w(const float* __restrict__ W, int rowbase,
                                        int cq, short* Wt, int tid) {
    #pragma unroll
    for (int i = 0; i < 4; ++i) {
        int idx = tid + i * 256;
        int mm = idx >> 4, c8 = (idx & 15) * 8;
        short8 v = load8f(W, (size_t)(rowbase + mm) * CIN + cq * 128 + c8);
        *(short8*)&Wt[mm * TS + c8] = v;
    }
}

// ---------------------------------------------------------------------------
// proj_nm: bq[n][m] = sum_c Wb[m][c] x[b][c][n]; ckT[n][m] likewise with Wc.
// grid: (64 nblk, BATCH). Both sels in one block; x staged once per c-quarter.
// ---------------------------------------------------------------------------
__global__ __launch_bounds__(256) void proj_nm_kernel(
    const float* __restrict__ x, const float* __restrict__ Wb,
    const float* __restrict__ Wc, short* __restrict__ bq,
    short* __restrict__ ckT)
{
    const int nblk = blockIdx.x, b = blockIdx.y;
    const int tid = threadIdx.x;
    const int wave = tid >> 6, lane = tid & 63, q = lane >> 4, lx = lane & 15;
    const int n0 = nblk * 64;

    __shared__ short xT[64 * TS];
    __shared__ short Wt[2][64 * TS];

    f32x4 acc[2][4];
    #pragma unroll
    for (int s = 0; s < 2; ++s)
        #pragma unroll
        for (int m = 0; m < 4; ++m) acc[s][m] = (f32x4){0.f, 0.f, 0.f, 0.f};

    stage_x(x, b, n0, 0, xT, tid);
    stage_w(Wb, 0, 0, Wt[0], tid);
    __syncthreads();

    for (int cq = 0; cq < 4; ++cq) {
        #pragma unroll
        for (int sel = 0; sel < 2; ++sel) {
            const int cur = sel & 1, nxt = cur ^ 1;
            // prestage next W tile into the buffer nobody is reading
            if (sel == 0) stage_w(Wc, 0, cq, Wt[nxt], tid);
            else if (cq < 3) stage_w(Wb, 0, cq + 1, Wt[nxt], tid);
            // compute: A = xT rows (n), B = Wt rows (m) -> acc[sel][mt]
            const short* arow = &xT[(wave * 16 + lx) * TS];
            #pragma unroll
            for (int cs = 0; cs < 4; ++cs) {
                short8 a = *(const short8*)(arow + cs * 32 + q * 8);
                #pragma unroll
                for (int mt = 0; mt < 4; ++mt) {
                    short8 bb = *(const short8*)&Wt[cur][(mt * 16 + lx) * TS + cs * 32 + q * 8];
                    acc[sel][mt] = MFMA16(a, bb, acc[sel][mt]);
                }
            }
            __syncthreads();
        }
        if (cq < 3) { stage_x(x, b, n0, cq + 1, xT, tid); __syncthreads(); }
    }

    #pragma unroll
    for (int sel = 0; sel < 2; ++sel) {
        short* dst = sel ? ckT : bq;
        #pragma unroll
        for (int mt = 0; mt < 4; ++mt)
            #pragma unroll
            for (int r = 0; r < 4; ++r) {
                int n = n0 + wave * 16 + q * 4 + r;
                dst[((size_t)b * NPIX + n) * 64 + mt * 16 + lx] = f2bs(acc[sel][mt][r]);
            }
    }
}

// ---------------------------------------------------------------------------
// proj_on: dvT[o][n] = sum_c Wd[o_base_W + o][c] x[b][c][n], transposed out.
// grid: (64 nblk, BATCH). All NOP*64 o-rows accumulated in registers;
// x staged once per c-quarter, W double-buffered.
// ---------------------------------------------------------------------------
template <int NOP>
__global__ __launch_bounds__(256) void proj_on_kernel(
    const float* __restrict__ x, const float* __restrict__ Wd, int o_base_W,
    short* __restrict__ dvT, int dv_rows)
{
    const int nblk = blockIdx.x, b = blockIdx.y;
    const int tid = threadIdx.x;
    const int wave = tid >> 6, lane = tid & 63, q = lane >> 4, lx = lane & 15;
    const int n0 = nblk * 64;

    __shared__ short xT[64 * TS];
    __shared__ short Wt[2][64 * TS];

    f32x4 acc[NOP][4];
    #pragma unroll
    for (int o = 0; o < NOP; ++o)
        #pragma unroll
        for (int n = 0; n < 4; ++n) acc[o][n] = (f32x4){0.f, 0.f, 0.f, 0.f};

    stage_x(x, b, n0, 0, xT, tid);
    stage_w(Wd, o_base_W, 0, Wt[0], tid);
    __syncthreads();

    for (int cq = 0; cq < 4; ++cq) {
        #pragma unroll
        for (int op = 0; op < NOP; ++op) {
            const int cur = op & 1, nxt = cur ^ 1;   // NOP even: parity = op&1
            if (op + 1 < NOP) stage_w(Wd, o_base_W + (op + 1) * 64, cq, Wt[nxt], tid);
            else if (cq < 3)  stage_w(Wd, o_base_W, cq + 1, Wt[nxt], tid);
            // compute: A = Wt rows (o), B = xT rows (n) -> acc[op][nt]
            #pragma unroll
            for (int cs = 0; cs < 4; ++cs) {
                short8 a = *(const short8*)&Wt[cur][(wave * 16 + lx) * TS + cs * 32 + q * 8];
                #pragma unroll
                for (int nt = 0; nt < 4; ++nt) {
                    short8 bb = *(const short8*)&xT[(nt * 16 + lx) * TS + cs * 32 + q * 8];
                    acc[op][nt] = MFMA16(a, bb, acc[op][nt]);
                }
            }
            __syncthreads();
        }
        if (cq < 3) { stage_x(x, b, n0, cq + 1, xT, tid); __syncthreads(); }
    }

    #pragma unroll
    for (int op = 0; op < NOP; ++op)
        #pragma unroll
        for (int nt = 0; nt < 4; ++nt)
            #pragma unroll
            for (int r = 0; r < 4; ++r) {
                int o = op * 64 + wave * 16 + q * 4 + r;
                dvT[((size_t)b * dv_rows + o) * NPIX + n0 + nt * 16 + lx] = f2bs(acc[op][nt][r]);
            }
}

// ---------------------------------------------------------------------------
// attn v4 (UNCHANGED this round): 32x32x16 MFMA, S^T trick (in-register P),
// __expf fast exp, manual packed bf16 conversion. Block 128n x 128o.
// grid: (32 nblk, och, BATCH)
// ---------------------------------------------------------------------------
__global__ __launch_bounds__(256, 2) void attn_kernel(
    const short* __restrict__ bq, const short* __restrict__ ckT,
    const short* __restrict__ dvT, int dv_rows, int och_base,
    const float* __restrict__ x, const float* __restrict__ gamma,
    float* __restrict__ out)
{
    const int nblk = blockIdx.x, och_l = blockIdx.y, b = blockIdx.z;
    const int tid = threadIdx.x;
    const int wave = tid >> 6, lane = tid & 63;
    const int h = lane >> 5, ln = lane & 31;
    const int och = och_base + och_l;
    const int obuf0 = (dv_rows == 512) ? och_l * 128 : 0;
    const int n = nblk * 128 + wave * 32 + ln;   // this lane's n column

    __shared__ short cks[64 * 72];    // [kp_staged(permuted)][m]
    __shared__ short dvs[128 * 72];   // [o][kp] natural order

    const float g = gamma[0];

    // persistent bq B-frags: B[m][n], lane col n, rows m = ms*16 + 8h + j
    short8 bm[4];
    {
        const short* bqp = bq + ((size_t)b * NPIX + n) * 64 + h * 8;
        #pragma unroll
        for (int ms = 0; ms < 4; ++ms) bm[ms] = *(const short8*)(bqp + ms * 16);
    }

    // staging pointers (register-prefetch)
    const short* pck[2]; short* qck[2];
    #pragma unroll
    for (int i = 0; i < 2; ++i) {
        int slot = tid + i * 256;
        int p = slot >> 3, c8 = (slot & 7) * 8;
        int srow = (p & ~15) | sigma16(p & 15);      // permuted source row
        pck[i] = ckT + ((size_t)b * NPIX + srow) * 64 + c8;
        qck[i] = &cks[p * 72 + c8];
    }
    const short* pdv[4]; short* qdv[4];
    #pragma unroll
    for (int i = 0; i < 4; ++i) {
        int slot = tid + i * 256;
        int o = slot >> 3, c8 = (slot & 7) * 8;
        pdv[i] = dvT + ((size_t)b * dv_rows + obuf0 + o) * NPIX + c8;
        qdv[i] = &dvs[o * 72 + c8];
    }

    // stage chunk 0
    short8 vck[2], vdv[4];
    #pragma unroll
    for (int i = 0; i < 2; ++i) vck[i] = *(const short8*)pck[i];
    #pragma unroll
    for (int i = 0; i < 4; ++i) vdv[i] = *(const short8*)pdv[i];
    #pragma unroll
    for (int i = 0; i < 2; ++i) *(short8*)qck[i] = vck[i];
    #pragma unroll
    for (int i = 0; i < 4; ++i) *(short8*)qdv[i] = vdv[i];
    __syncthreads();

    f32x16 acc[4];
    #pragma unroll
    for (int i = 0; i < 4; ++i)
        #pragma unroll
        for (int r = 0; r < 16; ++r) acc[i][r] = 0.f;
    float l_run = 0.f;

    for (int k0 = 0; k0 < NPIX; k0 += 64) {
        const bool more = (k0 + 64) < NPIX;
        if (more) {
            #pragma unroll
            for (int i = 0; i < 2; ++i) { pck[i] += 64 * 64; vck[i] = *(const short8*)pck[i]; }
            #pragma unroll
            for (int i = 0; i < 4; ++i) { pdv[i] += 64;      vdv[i] = *(const short8*)pdv[i]; }
        }

        // scores S^T: D[kp][n], 2 kp-tiles of 32 (natural-log units)
        f32x16 S[2];
        #pragma unroll
        for (int kpt = 0; kpt < 2; ++kpt) {
            f32x16 t;
            #pragma unroll
            for (int r = 0; r < 16; ++r) t[r] = 0.f;
            #pragma unroll
            for (int ms = 0; ms < 4; ++ms) {
                short8 a = *(const short8*)&cks[(kpt * 32 + ln) * 72 + ms * 16 + h * 8];
                t = MFMA32(a, bm[ms], t);
            }
            S[kpt] = t;
        }

        // p = e^s via __expf; pack pairs manually.
        short8 Bp[2][2];
        #pragma unroll
        for (int kpt = 0; kpt < 2; ++kpt) {
            float e[16];
            #pragma unroll
            for (int r = 0; r < 16; ++r) { e[r] = __expf(S[kpt][r]); l_run += e[r]; }
            #pragma unroll
            for (int sp = 0; sp < 2; ++sp) {
                union { unsigned w[4]; short8 s; } bp;
                #pragma unroll
                for (int j = 0; j < 4; ++j)
                    bp.w[j] = pack2bf(e[sp * 8 + j * 2], e[sp * 8 + j * 2 + 1]);
                Bp[kpt][sp] = bp.s;
            }
        }

        // PV: D[o][n] += dv(A) * P(B), kp-steps of 16
        #pragma unroll
        for (int s = 0; s < 4; ++s) {
            short8 bfrag = Bp[s >> 1][s & 1];
            #pragma unroll
            for (int ot = 0; ot < 4; ++ot) {
                short8 a = *(const short8*)&dvs[(ot * 32 + ln) * 72 + s * 16 + h * 8];
                acc[ot] = MFMA32(a, bfrag, acc[ot]);
            }
        }

        __syncthreads();
        if (more) {
            #pragma unroll
            for (int i = 0; i < 2; ++i) *(short8*)qck[i] = vck[i];
            #pragma unroll
            for (int i = 0; i < 4; ++i) *(short8*)qdv[i] = vdv[i];
            __syncthreads();
        }
    }

    // finalize l (lane ^ 32 holds the other h-half of this n's kp sums)
    float l_tot = l_run + __shfl_xor(l_run, 32, 64);
    const float scale = g / l_tot;

    // epilogue: out[b][o][n] = acc*scale + x (coalesced across lanes in n)
    #pragma unroll
    for (int ot = 0; ot < 4; ++ot) {
        #pragma unroll
        for (int r = 0; r < 16; ++r) {
            int o = och * 128 + ot * 32 + (r & 3) + 8 * (r >> 2) + 4 * h;
            size_t idx = ((size_t)b * CIN + o) * NPIX + n;
            out[idx] = acc[ot][r] * scale + x[idx];
        }
    }
}

// ---------------------------------------------------------------------------
extern "C" void kernel_launch(void* const* d_in, const int* in_sizes, int n_in,
                              void* d_out, int out_size, void* d_ws, size_t ws_size,
                              hipStream_t stream) {
    (void)in_sizes; (void)n_in; (void)out_size;
    const float* x     = (const float*)d_in[0];
    const float* Wb    = (const float*)d_in[1];
    const float* Wc    = (const float*)d_in[2];
    const float* Wd    = (const float*)d_in[3];
    const float* gamma = (const float*)d_in[4];
    float* out = (float*)d_out;

    // ws: bq bf16 B*N*64 (2MB) | ckT (2MB) | dvT (16MB full / 4MB chunked)
    short* bq  = (short*)d_ws;
    short* ckT = bq + (size_t)BATCH * NPIX * MIDC;
    short* dvT = ckT + (size_t)BATCH * NPIX * MIDC;
    const size_t fixed = 2 * (size_t)BATCH * NPIX * MIDC * 2;
    const size_t full_need = fixed + (size_t)BATCH * NPIX * CIN * 2;

    proj_nm_kernel<<<dim3(64, BATCH), 256, 0, stream>>>(x, Wb, Wc, bq, ckT);

    if (ws_size >= full_need) {
        proj_on_kernel<8><<<dim3(64, BATCH), 256, 0, stream>>>(x, Wd, 0, dvT, 512);
        attn_kernel<<<dim3(32, 4, BATCH), 256, 0, stream>>>(
            bq, ckT, dvT, 512, 0, x, gamma, out);
    } else {
        for (int qq = 0; qq < 4; ++qq) {
            proj_on_kernel<2><<<dim3(64, BATCH), 256, 0, stream>>>(
                x, Wd, qq * 128, dvT, 128);
            attn_kernel<<<dim3(32, 1, BATCH), 256, 0, stream>>>(
                bq, ckT, dvT, 128, qq, x, gamma, out);
        }
    }
}

// Round 2
// 236.155 us; speedup vs baseline: 1.1188x; 1.0851x over previous
//
#include <hip/hip_runtime.h>
#include <hip/hip_bf16.h>

#define CIN 512
#define NPIX 4096
#define MIDC 64
#define BATCH 4

typedef __hip_bfloat16 bf16;
typedef __attribute__((ext_vector_type(8))) short short8;
typedef __attribute__((ext_vector_type(16))) float f32x16;
typedef __attribute__((ext_vector_type(4))) float f32x4;

#define MFMA16(a, b, c) __builtin_amdgcn_mfma_f32_16x16x32_bf16(a, b, c, 0, 0, 0)
#define MFMA32(a, b, c) __builtin_amdgcn_mfma_f32_32x32x16_bf16(a, b, c, 0, 0, 0)

// cheap fp32 -> bf16 (round-half-up; inputs finite, no NaN path needed)
__device__ __forceinline__ short f2bs(float f) {
    unsigned u = __float_as_uint(f);
    return (short)((u + 0x8000u) >> 16);
}
// pack two fp32 -> bf16x2 in one uint (lo = a, hi = b)
__device__ __forceinline__ unsigned pack2bf(float a, float b) {
    unsigned ua = __float_as_uint(a), ub = __float_as_uint(b);
    return ((ua + 0x8000u) >> 16) | ((ub + 0x8000u) & 0xFFFF0000u);
}

// load 8 consecutive fp32 elements, convert to bf16 shorts (packed)
__device__ __forceinline__ short8 load8f(const float* p, size_t idx) {
    const float* q = p + idx;
    float4 u = *(const float4*)q;
    float4 v = *(const float4*)(q + 4);
    union { unsigned w[4]; short8 s; } r;
    r.w[0] = pack2bf(u.x, u.y);
    r.w[1] = pack2bf(u.z, u.w);
    r.w[2] = pack2bf(v.x, v.y);
    r.w[3] = pack2bf(v.z, v.w);
    return r.s;
}

// kp-row permutation for ck staging: within each 16, swap quartets [4,8)<->[8,12).
__device__ __forceinline__ int sigma16(int p) {
    int g = (p >> 2) & 3;
    return (g == 1) ? p + 4 : (g == 2) ? p - 4 : p;
}

#define TS 136

// ---------------------------------------------------------------------------
// Packed bf16 W: rows 0..511 = Wd, 512..575 = Wb, 576..639 = Wc. Static
// device allocation (no ws needed). Written by wprep each launch.
// ---------------------------------------------------------------------------
__device__ __align__(16) short g_wbf[640 * 512];

__global__ __launch_bounds__(256) void wprep_kernel(
    const float* __restrict__ Wd, const float* __restrict__ Wb,
    const float* __restrict__ Wc)
{
    int t = blockIdx.x * 256 + threadIdx.x;   // one short8 per thread, 40960 total
    int g = t >> 6, c8 = (t & 63) * 8;
    const float* src = (g < 512) ? Wd + (size_t)g * CIN
                     : (g < 576) ? Wb + (size_t)(g - 512) * CIN
                                 : Wc + (size_t)(g - 576) * CIN;
    *(short8*)&g_wbf[(size_t)g * CIN + c8] = load8f(src, c8);
}

// ---------------------------------------------------------------------------
// proj_fused: one block per (64-n tile, batch); 512 threads = 8 waves.
// Computes ALL 640 output rows (dvT, bq, ckT). x staged once per c-quarter in
// XOR-swizzled LDS (conflict-free transpose writes); W fragments loaded
// directly from global bf16 (L2-hot; each wave owns its 16 A-rows/panel).
// Only 2 barriers per c-quarter; B-fragments register-cached across panels.
// ---------------------------------------------------------------------------
__global__ __launch_bounds__(512, 2) void proj_fused_kernel(
    const float* __restrict__ x,
    short* __restrict__ bq, short* __restrict__ ckT, short* __restrict__ dvT)
{
    const int nblk = blockIdx.x, b = blockIdx.y;
    const int tid = threadIdx.x;
    const int w = tid >> 6, lane = tid & 63, q = lane >> 4, lx = lane & 15;
    const int n0 = nblk * 64;

    __shared__ __align__(16) short xT[64 * TS];

    // per-wave A-row base pointers: panel p rows p*128 + w*16 + lx
    const short* wp[5];
    #pragma unroll
    for (int p = 0; p < 5; ++p)
        wp[p] = g_wbf + ((size_t)(p * 128 + w * 16 + lx)) * CIN;

    f32x4 acc[5][4];
    #pragma unroll
    for (int p = 0; p < 5; ++p)
        #pragma unroll
        for (int nt = 0; nt < 4; ++nt) acc[p][nt] = (f32x4){0.f, 0.f, 0.f, 0.f};

    // x staging geometry: thread -> (cc_i = tid>>3 + i*64, nn = (tid&7)*8),
    // element (row=nn+e, c=cc) stored at col (cc ^ (row&56)) -> conflict-free.
    const int nn = (tid & 7) * 8;
    const int ccl = tid >> 3;            // 0..63
    const int swr = nn & 56;             // row-group swizzle (const across e)
    const size_t xbase = (size_t)b * CIN * NPIX + n0 + nn;

    short8 xv[2];
    #pragma unroll
    for (int i = 0; i < 2; ++i)
        xv[i] = load8f(x, xbase + (size_t)(ccl + i * 64) * NPIX);
    #pragma unroll
    for (int i = 0; i < 2; ++i) {
        int col = (ccl + i * 64) ^ swr;
        #pragma unroll
        for (int e = 0; e < 8; ++e) xT[(nn + e) * TS + col] = xv[i][e];
    }
    __syncthreads();

    #pragma unroll
    for (int cq = 0; cq < 4; ++cq) {
        // B-fragments for this c-quarter (reused across all 5 panels)
        short8 Bf[4][4];
        #pragma unroll
        for (int nt = 0; nt < 4; ++nt) {
            const short* base = &xT[(nt * 16 + lx) * TS];
            const int sw = (nt * 16 + lx) & 56;
            #pragma unroll
            for (int cs = 0; cs < 4; ++cs)
                Bf[cs][nt] = *(const short8*)(base + ((cs * 32 + q * 8) ^ sw));
        }
        __syncthreads();   // all B reads done before anyone overwrites xT

        // prefetch next x-tile into registers (written to LDS at end of cq)
        if (cq < 3) {
            #pragma unroll
            for (int i = 0; i < 2; ++i)
                xv[i] = load8f(x, xbase + (size_t)((cq + 1) * 128 + ccl + i * 64) * NPIX);
        }

        // panel sweep, distance-2 register pipeline on A (global bf16 loads)
        short8 Af[3][4];
        #pragma unroll
        for (int pp = 0; pp < 2; ++pp)
            #pragma unroll
            for (int cs = 0; cs < 4; ++cs)
                Af[pp][cs] = *(const short8*)(wp[pp] + cq * 128 + cs * 32 + q * 8);
        #pragma unroll
        for (int p = 0; p < 5; ++p) {
            if (p + 2 < 5) {
                #pragma unroll
                for (int cs = 0; cs < 4; ++cs)
                    Af[(p + 2) % 3][cs] =
                        *(const short8*)(wp[p + 2] + cq * 128 + cs * 32 + q * 8);
            }
            #pragma unroll
            for (int cs = 0; cs < 4; ++cs) {
                short8 a = Af[p % 3][cs];
                #pragma unroll
                for (int nt = 0; nt < 4; ++nt)
                    acc[p][nt] = MFMA16(a, Bf[cs][nt], acc[p][nt]);
            }
        }

        if (cq < 3) {
            #pragma unroll
            for (int i = 0; i < 2; ++i) {
                int col = (ccl + i * 64) ^ swr;
                #pragma unroll
                for (int e = 0; e < 8; ++e) xT[(nn + e) * TS + col] = xv[i][e];
            }
        }
        __syncthreads();
    }

    // epilogue: panels 0..3 -> dvT[o][n]; panel 4 -> bq (waves 0-3) / ckT (4-7)
    #pragma unroll
    for (int p = 0; p < 4; ++p)
        #pragma unroll
        for (int nt = 0; nt < 4; ++nt)
            #pragma unroll
            for (int r = 0; r < 4; ++r) {
                int o = p * 128 + w * 16 + q * 4 + r;
                dvT[((size_t)b * CIN + o) * NPIX + n0 + nt * 16 + lx] =
                    f2bs(acc[p][nt][r]);
            }
    {
        short* dst = (w < 4) ? bq : ckT;
        const int mbase = (w & 3) * 16;
        #pragma unroll
        for (int nt = 0; nt < 4; ++nt)
            #pragma unroll
            for (int r = 0; r < 4; ++r) {
                int nn2 = n0 + nt * 16 + lx;
                dst[((size_t)b * NPIX + nn2) * 64 + mbase + q * 4 + r] =
                    f2bs(acc[4][nt][r]);
            }
    }
}

// ---------------------------------------------------------------------------
// Fallback-path projection kernels (small-ws chunked path only), unchanged.
// ---------------------------------------------------------------------------
__device__ __forceinline__ void stage_x(const float* __restrict__ x, int b, int n0,
                                        int cq, short* xT, int tid) {
    #pragma unroll
    for (int i = 0; i < 4; ++i) {
        int idx = tid + i * 256;
        int cc = idx >> 3, nnn = (idx & 7) * 8;
        short8 v = load8f(x, (size_t)b * CIN * NPIX + (size_t)(cq * 128 + cc) * NPIX + n0 + nnn);
        #pragma unroll
        for (int e = 0; e < 8; ++e) xT[(nnn + e) * TS + cc] = v[e];
    }
}
__device__ __forceinline__ void stage_w(const float* __restrict__ W, int rowbase,
                                        int cq, short* Wt, int tid) {
    #pragma unroll
    for (int i = 0; i < 4; ++i) {
        int idx = tid + i * 256;
        int mm = idx >> 4, c8 = (idx & 15) * 8;
        short8 v = load8f(W, (size_t)(rowbase + mm) * CIN + cq * 128 + c8);
        *(short8*)&Wt[mm * TS + c8] = v;
    }
}

__global__ __launch_bounds__(256) void proj_nm_kernel(
    const float* __restrict__ x, const float* __restrict__ Wb,
    const float* __restrict__ Wc, short* __restrict__ bq,
    short* __restrict__ ckT)
{
    const int nblk = blockIdx.x, b = blockIdx.y;
    const int tid = threadIdx.x;
    const int wave = tid >> 6, lane = tid & 63, q = lane >> 4, lx = lane & 15;
    const int n0 = nblk * 64;

    __shared__ __align__(16) short xT[64 * TS];
    __shared__ __align__(16) short Wt[2][64 * TS];

    f32x4 acc[2][4];
    #pragma unroll
    for (int s = 0; s < 2; ++s)
        #pragma unroll
        for (int m = 0; m < 4; ++m) acc[s][m] = (f32x4){0.f, 0.f, 0.f, 0.f};

    stage_x(x, b, n0, 0, xT, tid);
    stage_w(Wb, 0, 0, Wt[0], tid);
    __syncthreads();

    for (int cq = 0; cq < 4; ++cq) {
        #pragma unroll
        for (int sel = 0; sel < 2; ++sel) {
            const int cur = sel & 1, nxt = cur ^ 1;
            if (sel == 0) stage_w(Wc, 0, cq, Wt[nxt], tid);
            else if (cq < 3) stage_w(Wb, 0, cq + 1, Wt[nxt], tid);
            const short* arow = &xT[(wave * 16 + lx) * TS];
            #pragma unroll
            for (int cs = 0; cs < 4; ++cs) {
                short8 a = *(const short8*)(arow + cs * 32 + q * 8);
                #pragma unroll
                for (int mt = 0; mt < 4; ++mt) {
                    short8 bb = *(const short8*)&Wt[cur][(mt * 16 + lx) * TS + cs * 32 + q * 8];
                    acc[sel][mt] = MFMA16(a, bb, acc[sel][mt]);
                }
            }
            __syncthreads();
        }
        if (cq < 3) { stage_x(x, b, n0, cq + 1, xT, tid); __syncthreads(); }
    }

    #pragma unroll
    for (int sel = 0; sel < 2; ++sel) {
        short* dst = sel ? ckT : bq;
        #pragma unroll
        for (int mt = 0; mt < 4; ++mt)
            #pragma unroll
            for (int r = 0; r < 4; ++r) {
                int n = n0 + wave * 16 + q * 4 + r;
                dst[((size_t)b * NPIX + n) * 64 + mt * 16 + lx] = f2bs(acc[sel][mt][r]);
            }
    }
}

template <int NOP>
__global__ __launch_bounds__(256) void proj_on_kernel(
    const float* __restrict__ x, const float* __restrict__ Wd, int o_base_W,
    short* __restrict__ dvT, int dv_rows)
{
    const int nblk = blockIdx.x, b = blockIdx.y;
    const int tid = threadIdx.x;
    const int wave = tid >> 6, lane = tid & 63, q = lane >> 4, lx = lane & 15;
    const int n0 = nblk * 64;

    __shared__ __align__(16) short xT[64 * TS];
    __shared__ __align__(16) short Wt[2][64 * TS];

    f32x4 acc[NOP][4];
    #pragma unroll
    for (int o = 0; o < NOP; ++o)
        #pragma unroll
        for (int n = 0; n < 4; ++n) acc[o][n] = (f32x4){0.f, 0.f, 0.f, 0.f};

    stage_x(x, b, n0, 0, xT, tid);
    stage_w(Wd, o_base_W, 0, Wt[0], tid);
    __syncthreads();

    for (int cq = 0; cq < 4; ++cq) {
        #pragma unroll
        for (int op = 0; op < NOP; ++op) {
            const int cur = op & 1, nxt = cur ^ 1;
            if (op + 1 < NOP) stage_w(Wd, o_base_W + (op + 1) * 64, cq, Wt[nxt], tid);
            else if (cq < 3)  stage_w(Wd, o_base_W, cq + 1, Wt[nxt], tid);
            #pragma unroll
            for (int cs = 0; cs < 4; ++cs) {
                short8 a = *(const short8*)&Wt[cur][(wave * 16 + lx) * TS + cs * 32 + q * 8];
                #pragma unroll
                for (int nt = 0; nt < 4; ++nt) {
                    short8 bb = *(const short8*)&xT[(nt * 16 + lx) * TS + cs * 32 + q * 8];
                    acc[op][nt] = MFMA16(a, bb, acc[op][nt]);
                }
            }
            __syncthreads();
        }
        if (cq < 3) { stage_x(x, b, n0, cq + 1, xT, tid); __syncthreads(); }
    }

    #pragma unroll
    for (int op = 0; op < NOP; ++op)
        #pragma unroll
        for (int nt = 0; nt < 4; ++nt)
            #pragma unroll
            for (int r = 0; r < 4; ++r) {
                int o = op * 64 + wave * 16 + q * 4 + r;
                dvT[((size_t)b * dv_rows + o) * NPIX + n0 + nt * 16 + lx] = f2bs(acc[op][nt][r]);
            }
}

// ---------------------------------------------------------------------------
// attn v4 (UNCHANGED): 32x32x16 MFMA, S^T trick (in-register P),
// __expf fast exp, manual packed bf16 conversion. Block 128n x 128o.
// grid: (32 nblk, och, BATCH)
// ---------------------------------------------------------------------------
__global__ __launch_bounds__(256, 2) void attn_kernel(
    const short* __restrict__ bq, const short* __restrict__ ckT,
    const short* __restrict__ dvT, int dv_rows, int och_base,
    const float* __restrict__ x, const float* __restrict__ gamma,
    float* __restrict__ out)
{
    const int nblk = blockIdx.x, och_l = blockIdx.y, b = blockIdx.z;
    const int tid = threadIdx.x;
    const int wave = tid >> 6, lane = tid & 63;
    const int h = lane >> 5, ln = lane & 31;
    const int och = och_base + och_l;
    const int obuf0 = (dv_rows == 512) ? och_l * 128 : 0;
    const int n = nblk * 128 + wave * 32 + ln;   // this lane's n column

    __shared__ short cks[64 * 72];    // [kp_staged(permuted)][m]
    __shared__ short dvs[128 * 72];   // [o][kp] natural order

    const float g = gamma[0];

    // persistent bq B-frags: B[m][n], lane col n, rows m = ms*16 + 8h + j
    short8 bm[4];
    {
        const short* bqp = bq + ((size_t)b * NPIX + n) * 64 + h * 8;
        #pragma unroll
        for (int ms = 0; ms < 4; ++ms) bm[ms] = *(const short8*)(bqp + ms * 16);
    }

    // staging pointers (register-prefetch)
    const short* pck[2]; short* qck[2];
    #pragma unroll
    for (int i = 0; i < 2; ++i) {
        int slot = tid + i * 256;
        int p = slot >> 3, c8 = (slot & 7) * 8;
        int srow = (p & ~15) | sigma16(p & 15);      // permuted source row
        pck[i] = ckT + ((size_t)b * NPIX + srow) * 64 + c8;
        qck[i] = &cks[p * 72 + c8];
    }
    const short* pdv[4]; short* qdv[4];
    #pragma unroll
    for (int i = 0; i < 4; ++i) {
        int slot = tid + i * 256;
        int o = slot >> 3, c8 = (slot & 7) * 8;
        pdv[i] = dvT + ((size_t)b * dv_rows + obuf0 + o) * NPIX + c8;
        qdv[i] = &dvs[o * 72 + c8];
    }

    // stage chunk 0
    short8 vck[2], vdv[4];
    #pragma unroll
    for (int i = 0; i < 2; ++i) vck[i] = *(const short8*)pck[i];
    #pragma unroll
    for (int i = 0; i < 4; ++i) vdv[i] = *(const short8*)pdv[i];
    #pragma unroll
    for (int i = 0; i < 2; ++i) *(short8*)qck[i] = vck[i];
    #pragma unroll
    for (int i = 0; i < 4; ++i) *(short8*)qdv[i] = vdv[i];
    __syncthreads();

    f32x16 acc[4];
    #pragma unroll
    for (int i = 0; i < 4; ++i)
        #pragma unroll
        for (int r = 0; r < 16; ++r) acc[i][r] = 0.f;
    float l_run = 0.f;

    for (int k0 = 0; k0 < NPIX; k0 += 64) {
        const bool more = (k0 + 64) < NPIX;
        if (more) {
            #pragma unroll
            for (int i = 0; i < 2; ++i) { pck[i] += 64 * 64; vck[i] = *(const short8*)pck[i]; }
            #pragma unroll
            for (int i = 0; i < 4; ++i) { pdv[i] += 64;      vdv[i] = *(const short8*)pdv[i]; }
        }

        // scores S^T: D[kp][n], 2 kp-tiles of 32 (natural-log units)
        f32x16 S[2];
        #pragma unroll
        for (int kpt = 0; kpt < 2; ++kpt) {
            f32x16 t;
            #pragma unroll
            for (int r = 0; r < 16; ++r) t[r] = 0.f;
            #pragma unroll
            for (int ms = 0; ms < 4; ++ms) {
                short8 a = *(const short8*)&cks[(kpt * 32 + ln) * 72 + ms * 16 + h * 8];
                t = MFMA32(a, bm[ms], t);
            }
            S[kpt] = t;
        }

        // p = e^s via __expf; pack pairs manually.
        short8 Bp[2][2];
        #pragma unroll
        for (int kpt = 0; kpt < 2; ++kpt) {
            float e[16];
            #pragma unroll
            for (int r = 0; r < 16; ++r) { e[r] = __expf(S[kpt][r]); l_run += e[r]; }
            #pragma unroll
            for (int sp = 0; sp < 2; ++sp) {
                union { unsigned w[4]; short8 s; } bp;
                #pragma unroll
                for (int j = 0; j < 4; ++j)
                    bp.w[j] = pack2bf(e[sp * 8 + j * 2], e[sp * 8 + j * 2 + 1]);
                Bp[kpt][sp] = bp.s;
            }
        }

        // PV: D[o][n] += dv(A) * P(B), kp-steps of 16
        #pragma unroll
        for (int s = 0; s < 4; ++s) {
            short8 bfrag = Bp[s >> 1][s & 1];
            #pragma unroll
            for (int ot = 0; ot < 4; ++ot) {
                short8 a = *(const short8*)&dvs[(ot * 32 + ln) * 72 + s * 16 + h * 8];
                acc[ot] = MFMA32(a, bfrag, acc[ot]);
            }
        }

        __syncthreads();
        if (more) {
            #pragma unroll
            for (int i = 0; i < 2; ++i) *(short8*)qck[i] = vck[i];
            #pragma unroll
            for (int i = 0; i < 4; ++i) *(short8*)qdv[i] = vdv[i];
            __syncthreads();
        }
    }

    // finalize l (lane ^ 32 holds the other h-half of this n's kp sums)
    float l_tot = l_run + __shfl_xor(l_run, 32, 64);
    const float scale = g / l_tot;

    // epilogue: out[b][o][n] = acc*scale + x (coalesced across lanes in n)
    #pragma unroll
    for (int ot = 0; ot < 4; ++ot) {
        #pragma unroll
        for (int r = 0; r < 16; ++r) {
            int o = och * 128 + ot * 32 + (r & 3) + 8 * (r >> 2) + 4 * h;
            size_t idx = ((size_t)b * CIN + o) * NPIX + n;
            out[idx] = acc[ot][r] * scale + x[idx];
        }
    }
}

// ---------------------------------------------------------------------------
extern "C" void kernel_launch(void* const* d_in, const int* in_sizes, int n_in,
                              void* d_out, int out_size, void* d_ws, size_t ws_size,
                              hipStream_t stream) {
    (void)in_sizes; (void)n_in; (void)out_size;
    const float* x     = (const float*)d_in[0];
    const float* Wb    = (const float*)d_in[1];
    const float* Wc    = (const float*)d_in[2];
    const float* Wd    = (const float*)d_in[3];
    const float* gamma = (const float*)d_in[4];
    float* out = (float*)d_out;

    // ws: bq bf16 B*N*64 (2MB) | ckT (2MB) | dvT (16MB full / 4MB chunked)
    short* bq  = (short*)d_ws;
    short* ckT = bq + (size_t)BATCH * NPIX * MIDC;
    short* dvT = ckT + (size_t)BATCH * NPIX * MIDC;
    const size_t fixed = 2 * (size_t)BATCH * NPIX * MIDC * 2;
    const size_t full_need = fixed + (size_t)BATCH * NPIX * CIN * 2;

    if (ws_size >= full_need) {
        wprep_kernel<<<dim3(160), 256, 0, stream>>>(Wd, Wb, Wc);
        proj_fused_kernel<<<dim3(64, BATCH), 512, 0, stream>>>(x, bq, ckT, dvT);
        attn_kernel<<<dim3(32, 4, BATCH), 256, 0, stream>>>(
            bq, ckT, dvT, 512, 0, x, gamma, out);
    } else {
        proj_nm_kernel<<<dim3(64, BATCH), 256, 0, stream>>>(x, Wb, Wc, bq, ckT);
        for (int qq = 0; qq < 4; ++qq) {
            proj_on_kernel<2><<<dim3(64, BATCH), 256, 0, stream>>>(
                x, Wd, qq * 128, dvT, 128);
            attn_kernel<<<dim3(32, 1, BATCH), 256, 0, stream>>>(
                bq, ckT, dvT, 128, qq, x, gamma, out);
        }
    }
}